// Round 7
// baseline (808.766 us; speedup 1.0000x reference)
//
#include <hip/hip_runtime.h>
#include <hip/hip_bf16.h>

// ---------------------------------------------------------------------------
// Multimodal LSTM (x3) -> concat -> PTP layer1 (8 windows, rank 16) -> PTP layer2
// Round 7: k_lstm7 — W streamed L2 -> VGPR 4-slot register ring via asm
// global_load_dwordx4 with counted vmcnt (distance-4 prefetch, no LDS hop).
// xp stored/read as bf16 (mm_proj writes halved). Math mapping identical to
// round-6 passing kernel.
// ---------------------------------------------------------------------------

namespace {
constexpr int kB  = 256;
constexpr int kT  = 32;
constexpr int kH  = 256;
constexpr int k4H = 1024;
constexpr int kNW = 8;
constexpr int kR  = 16;
constexpr int kO0 = 128;
constexpr int kO1 = 64;
constexpr int kD1 = 3073;   // 4*768 + 1
constexpr int kD2 = 1025;   // 8*128 + 1
}

typedef __attribute__((ext_vector_type(8))) short short8;   // 8 bf16 (4 VGPRs)
typedef __attribute__((ext_vector_type(4))) float f32x4;    // MFMA acc
typedef __attribute__((ext_vector_type(4))) unsigned int u32x4;

__device__ __forceinline__ unsigned int pack2bf(float a, float b) {
    unsigned int ua = __builtin_bit_cast(unsigned int, a);
    unsigned int ub = __builtin_bit_cast(unsigned int, b);
    return (ua >> 16) | (ub & 0xffff0000u);
}
__device__ __forceinline__ float bflo(unsigned int u) {
    return __builtin_bit_cast(float, u << 16);
}
__device__ __forceinline__ float bfhi(unsigned int u) {
    return __builtin_bit_cast(float, u & 0xffff0000u);
}
__device__ __forceinline__ float sigm(float x) {
    return 1.f / (1.f + __expf(-x));
}
__device__ __forceinline__ float tanh_fast(float x) {
    float a = fabsf(x);
    float t = 1.f - 2.f / (__expf(2.f * a) + 1.f);
    return copysignf(t, x);
}
__device__ __forceinline__ void gload4u(u32x4& dst, const unsigned int* p) {
    asm volatile("global_load_dwordx4 %0, %1, off" : "=v"(dst) : "v"(p) : "memory");
}
__device__ __forceinline__ uint2 gload2u(const unsigned short* p) {
    uint2 r;
    asm volatile("global_load_dwordx2 %0, %1, off" : "=v"(r) : "v"(p) : "memory");
    return r;
}

// ---------------- W_hh (4H,H) fp32 -> MFMA-B-fragment-linear bf16.
// Slab (net,w,s): 4 KB = [gate g][lane l] u32x4; lane l holds
// col = g*256 + w*16 + (l&15), k = s*32 + (l>>4)*8 + [0..8).
// uint index: (((net*16+w)*8+s)*4+g)*256 + l*4
__global__ void k_prep_wfrag(const float* __restrict__ wa, const float* __restrict__ wv,
                             const float* __restrict__ wtx, unsigned int* __restrict__ wfrag) {
    int g = blockIdx.x * 256 + threadIdx.x;     // 0 .. 98303
    int l  = g & 63;
    int gt = (g >> 6) & 3;
    int s  = (g >> 8) & 7;
    int w  = (g >> 11) & 15;
    int net = g >> 15;
    const float* W = (net == 0) ? wa : (net == 1) ? wv : wtx;
    const int col = gt * 256 + w * 16 + (l & 15);
    const int k0  = s * 32 + (l >> 4) * 8;
    const float* src = W + (size_t)col * 256 + k0;
    float4 f0 = *(const float4*)src;
    float4 f1 = *(const float4*)(src + 4);
    u32x4 v = { pack2bf(f0.x, f0.y), pack2bf(f0.z, f0.w),
                pack2bf(f1.x, f1.y), pack2bf(f1.z, f1.w) };
    *(u32x4*)&wfrag[(size_t)g * 4] = v;
}

// ---------------- MFMA GEMM (NT) for input projections, PERMUTED output cols,
// bf16 output: stored col n = w*64 + q*4 + g <-> orig gate-col g*256 + w*16 + q.
__global__ __launch_bounds__(512)
void k_mm_proj(const float* __restrict__ A, const float* __restrict__ W,
               const float* __restrict__ b1, const float* __restrict__ b2,
               unsigned short* __restrict__ C, int K) {
    __shared__ __align__(16) unsigned int As[256 * 20];
    __shared__ __align__(16) unsigned int Bs[128 * 20];
    const int tid  = threadIdx.x;
    const int lane = tid & 63;
    const int wid  = tid >> 6;
    const int wm   = wid >> 1, wn = wid & 1;
    const int m0 = blockIdx.x * 256, n0 = blockIdx.y * 128;
    const int nstep = K >> 5;

    const int ar = tid >> 1, akq = (tid & 1) * 16;
    const int br = tid >> 2, bkq = (tid & 3) * 8;
    const float* ap = A + (size_t)(m0 + ar) * K + akq;
    const int nn = n0 + br;
    const int worow = (nn & 3) * 256 + (nn >> 6) * 16 + ((nn >> 2) & 15);
    const float* wp = W + (size_t)worow * K + bkq;

    float4 aR[4], bR[2];
    auto loadA = [&](int s) {
#pragma unroll
        for (int i = 0; i < 4; ++i) aR[i] = *(const float4*)(ap + s * 32 + i * 4);
    };
    auto loadB = [&](int s) {
#pragma unroll
        for (int i = 0; i < 2; ++i) bR[i] = *(const float4*)(wp + s * 32 + i * 4);
    };

    f32x4 acc[4][4];
#pragma unroll
    for (int i = 0; i < 4; ++i)
#pragma unroll
        for (int j = 0; j < 4; ++j) acc[i][j] = (f32x4){0.f, 0.f, 0.f, 0.f};

    loadA(0); loadB(0);
    for (int s = 0; s < nstep; ++s) {
        __syncthreads();
        {
            u32x4 w0 = { pack2bf(aR[0].x, aR[0].y), pack2bf(aR[0].z, aR[0].w),
                         pack2bf(aR[1].x, aR[1].y), pack2bf(aR[1].z, aR[1].w) };
            u32x4 w1 = { pack2bf(aR[2].x, aR[2].y), pack2bf(aR[2].z, aR[2].w),
                         pack2bf(aR[3].x, aR[3].y), pack2bf(aR[3].z, aR[3].w) };
            *(u32x4*)&As[ar * 20 + (akq >> 1)]     = w0;
            *(u32x4*)&As[ar * 20 + (akq >> 1) + 4] = w1;
            u32x4 v0 = { pack2bf(bR[0].x, bR[0].y), pack2bf(bR[0].z, bR[0].w),
                         pack2bf(bR[1].x, bR[1].y), pack2bf(bR[1].z, bR[1].w) };
            *(u32x4*)&Bs[br * 20 + (bkq >> 1)] = v0;
        }
        __syncthreads();
        if (s + 1 < nstep) { loadA(s + 1); loadB(s + 1); }
        short8 af[4], bf[4];
#pragma unroll
        for (int i = 0; i < 4; ++i)
            af[i] = __builtin_bit_cast(short8,
                *(const u32x4*)&As[(wm * 64 + i * 16 + (lane & 15)) * 20 + (lane >> 4) * 4]);
#pragma unroll
        for (int j = 0; j < 4; ++j)
            bf[j] = __builtin_bit_cast(short8,
                *(const u32x4*)&Bs[(wn * 64 + j * 16 + (lane & 15)) * 20 + (lane >> 4) * 4]);
#pragma unroll
        for (int i = 0; i < 4; ++i)
#pragma unroll
            for (int j = 0; j < 4; ++j)
                acc[i][j] = __builtin_amdgcn_mfma_f32_16x16x32_bf16(af[i], bf[j], acc[i][j], 0, 0, 0);
    }
#pragma unroll
    for (int i = 0; i < 4; ++i) {
#pragma unroll
        for (int j = 0; j < 4; ++j) {
            const int col  = n0 + wn * 64 + j * 16 + (lane & 15);
            const int ocol = (col & 3) * 256 + (col >> 6) * 16 + ((col >> 2) & 15);
            const float badd = b1[ocol] + b2[ocol];
#pragma unroll
            for (int e = 0; e < 4; ++e) {
                const int row = m0 + wm * 64 + i * 16 + (lane >> 4) * 4 + e;
                const float v = acc[i][j][e] + badd;
                C[(size_t)row * 1024 + col] =
                    (unsigned short)(__builtin_bit_cast(unsigned int, v) >> 16);
            }
        }
    }
}

// ---------------- k_lstm7: MFMA recurrence, register-ring W pipeline.
// Block = (net, 16 batch rows). 16 waves; wave w owns dims [16w,16w+16) of all
// 4 gates. W slabs asm-loaded L2 -> 4-slot VGPR ring (distance-4 prefetch,
// counted vmcnt). h in 2x8KB XOR-swizzled LDS, 1 raw barrier/step.
__global__ __launch_bounds__(1024, 4)
void k_lstm7(const unsigned short* __restrict__ xp_a, const unsigned short* __restrict__ xp_v,
             const unsigned short* __restrict__ xp_t, const unsigned int* __restrict__ wfrag,
             unsigned short* __restrict__ hp) {
    const int bg  = blockIdx.x;            // 0..15
    const int net = blockIdx.y;            // 0=audio,1=video,2=text
    const int tid = threadIdx.x;
    const int l   = tid & 63;
    const int w   = tid >> 6;              // wave -> dim-slice [16w,16w+16)
    const unsigned short* xp = (net == 0) ? xp_a : (net == 1) ? xp_v : xp_t;
    const int coloff = (net == 0) ? 256 : (net == 1) ? 512 : 0;  // cat=[text,audio,video]

    __shared__ __align__(16) unsigned short hA[8192];     // 2 x 8 KB, XOR-swizzled
    for (int i = tid; i < 4096; i += 1024) ((unsigned int*)hA)[i] = 0u;

    const int q  = l & 15;
    const int r0 = (l >> 4) * 4;           // first of 4 batch rows this lane owns
    const int d  = w * 16 + q;             // dim within net

    const unsigned int* wb = wfrag + (size_t)(net * 16 + w) * 8192 + l * 4;
    const unsigned short* xr0 = xp + ((size_t)(bg * 16 + r0) * 32) * 1024 + w * 64 + q * 4;

    const unsigned int rbase = (unsigned int)q * 512;
    const unsigned int rxor  = (unsigned int)(q & 7) << 4;
    const unsigned int kofs  = (unsigned int)(l >> 4) * 16;

    float cc[4] = {0.f, 0.f, 0.f, 0.f};
    u32x4 b[4][4];        // [slot][gate] register ring
    uint2 xq[4];

    // prologue: slabs 0-3 -> slots 0-3 (16 loads), xp(t=0) (4 loads); queue = 20
#pragma unroll
    for (int s = 0; s < 4; ++s)
#pragma unroll
        for (int g = 0; g < 4; ++g)
            gload4u(b[s][g], wb + (s * 4 + g) * 256);
#pragma unroll
    for (int e = 0; e < 4; ++e)
        xq[e] = gload2u(xr0 + e * 32768);

    asm volatile("s_waitcnt lgkmcnt(0)" ::: "memory");
    __builtin_amdgcn_s_barrier();

#pragma unroll 1
    for (int t = 0; t < kT; ++t) {
        const unsigned int rbuf = (unsigned int)(t & 1) * 8192;
        const unsigned int wbuf = 8192u - rbuf;

        f32x4 acc[4];
#pragma unroll
        for (int g = 0; g < 4; ++g) acc[g] = (f32x4){0.f, 0.f, 0.f, 0.f};

#pragma unroll
        for (int s = 0; s < 8; ++s) {
            // slab s (4 loads) is the oldest needed entry in the vm queue
            if (s < 4) asm volatile("s_waitcnt vmcnt(16)" ::: "memory");
            else       asm volatile("s_waitcnt vmcnt(12)" ::: "memory");
            __builtin_amdgcn_sched_barrier(0);
            u32x4 af = *(const u32x4*)((const char*)hA + rbuf + rbase
                                       + (((unsigned)(s * 64) + kofs) ^ rxor));
            acc[0] = __builtin_amdgcn_mfma_f32_16x16x32_bf16(
                __builtin_bit_cast(short8, af), __builtin_bit_cast(short8, b[s & 3][0]), acc[0], 0, 0, 0);
            acc[1] = __builtin_amdgcn_mfma_f32_16x16x32_bf16(
                __builtin_bit_cast(short8, af), __builtin_bit_cast(short8, b[s & 3][1]), acc[1], 0, 0, 0);
            acc[2] = __builtin_amdgcn_mfma_f32_16x16x32_bf16(
                __builtin_bit_cast(short8, af), __builtin_bit_cast(short8, b[s & 3][2]), acc[2], 0, 0, 0);
            acc[3] = __builtin_amdgcn_mfma_f32_16x16x32_bf16(
                __builtin_bit_cast(short8, af), __builtin_bit_cast(short8, b[s & 3][3]), acc[3], 0, 0, 0);
            __builtin_amdgcn_sched_barrier(0);
            // prefetch slab s+4 into the slot consumed this iteration (W cyclic)
            const unsigned int* sp = wb + (unsigned)(((s + 4) & 7) * 4) * 256;
            gload4u(b[s & 3][0], sp);
            gload4u(b[s & 3][1], sp + 256);
            gload4u(b[s & 3][2], sp + 512);
            gload4u(b[s & 3][3], sp + 768);
        }

        // in-register activations (xq retired by s=4's vmcnt(12))
        float hv[4];
#pragma unroll
        for (int e = 0; e < 4; ++e) {
            float gi = acc[0][e] + bflo(xq[e].x);
            float gf = acc[1][e] + bfhi(xq[e].x);
            float gg = acc[2][e] + bflo(xq[e].y);
            float go = acc[3][e] + bfhi(xq[e].y);
            cc[e] = sigm(gf) * cc[e] + sigm(gi) * tanh_fast(gg);
            hv[e] = sigm(go) * tanh_fast(cc[e]);
        }

        // issue next step's xp (full-step lead); clamp keeps last issue in-bounds
        const int tn = (t < kT - 1) ? (t + 1) : (kT - 1);
#pragma unroll
        for (int e = 0; e < 4; ++e)
            xq[e] = gload2u(xr0 + (size_t)tn * 1024 + e * 32768);

        // stores: hA (next A operand, swizzled) + hp (PTP1 fragment layout)
        const int kk = (t & 3) * 768 + coloff + d;
        const int sp2 = kk >> 5;
        unsigned short* hpb = hp +
            ((((size_t)((t >> 2) * 96 + sp2) * 16 + bg) * 64
              + (unsigned)(r0 | (((kk >> 3) & 3) << 4))) * 8 + (kk & 7));
#pragma unroll
        for (int e = 0; e < 4; ++e) {
            const unsigned short hb =
                (unsigned short)(__builtin_bit_cast(unsigned int, hv[e]) >> 16);
            const int row = r0 + e;
            *(unsigned short*)((char*)hA + wbuf + (unsigned)row * 512
                               + (((unsigned)(2 * d)) ^ (((unsigned)(row & 7)) << 4))) = hb;
            hpb[e * 8] = hb;
        }
        asm volatile("s_waitcnt lgkmcnt(0)" ::: "memory");
        __builtin_amdgcn_s_barrier();
    }
}

// ---------------- PTP1 MFMA GEMM: z1p[ks][n][b][r][o] = sum_{d in ks-half} x*F
// A direct from hp (fragment-packed bf16); B fp32 staged->bf16 LDS (pitch 48).
__global__ __launch_bounds__(512)
void k_ptp1_mfma(const unsigned int* __restrict__ hp, const float* __restrict__ factor,
                 float* __restrict__ z1p) {
    __shared__ __align__(16) unsigned short Bs[128 * 48];
    const int tid  = threadIdx.x;
    const int lane = tid & 63;
    const int wid  = tid >> 6;
    const int r  = blockIdx.x >> 1;
    const int ks = blockIdx.x & 1;
    const int n  = blockIdx.y;

    const int bd = tid >> 4;
    const int bo = (tid & 15) * 8;
    const float* fp = factor + ((size_t)(n * kR + r) * kD1 + 1 + ks * 1536 + bd) * kO0 + bo;
    const unsigned int* ha = hp + ((size_t)n * 96 + ks * 48) * 16 * 256 + lane * 4;

    f32x4 acc[2][8];
#pragma unroll
    for (int i = 0; i < 2; ++i)
#pragma unroll
        for (int j = 0; j < 8; ++j) acc[i][j] = (f32x4){0.f, 0.f, 0.f, 0.f};

    float4 br[2][2];
    u32x4 af[2][2];
    auto loadB = [&](int s, int qq) {
        br[qq][0] = *(const float4*)(fp + (size_t)s * 32 * kO0);
        br[qq][1] = *(const float4*)(fp + (size_t)s * 32 * kO0 + 4);
    };
    auto loadA = [&](int s, int qq) {
#pragma unroll
        for (int i = 0; i < 2; ++i)
            af[qq][i] = *(const u32x4*)(ha + ((size_t)s * 16 + (wid * 2 + i)) * 256);
    };
    loadB(0, 0); loadA(0, 0);
#pragma unroll 2
    for (int s = 0; s < 48; ++s) {
        const int qq = s & 1;
        __syncthreads();
        {
            float bv[8] = {br[qq][0].x, br[qq][0].y, br[qq][0].z, br[qq][0].w,
                           br[qq][1].x, br[qq][1].y, br[qq][1].z, br[qq][1].w};
#pragma unroll
            for (int i = 0; i < 8; ++i)
                Bs[(bo + i) * 48 + bd] =
                    (unsigned short)(__builtin_bit_cast(unsigned int, bv[i]) >> 16);
        }
        __syncthreads();
        if (s + 1 < 48) { loadB(s + 1, qq ^ 1); loadA(s + 1, qq ^ 1); }
        short8 bf[8];
#pragma unroll
        for (int j = 0; j < 8; ++j)
            bf[j] = __builtin_bit_cast(short8,
                *(const u32x4*)&Bs[(j * 16 + (lane & 15)) * 48 + (lane >> 4) * 8]);
#pragma unroll
        for (int i = 0; i < 2; ++i)
#pragma unroll
            for (int j = 0; j < 8; ++j)
                acc[i][j] = __builtin_amdgcn_mfma_f32_16x16x32_bf16(
                    __builtin_bit_cast(short8, af[qq][i]), bf[j], acc[i][j], 0, 0, 0);
    }
    const size_t zb = ((size_t)ks * 8 + n) * 256;
#pragma unroll
    for (int i = 0; i < 2; ++i) {
#pragma unroll
        for (int j = 0; j < 8; ++j) {
            const int col = j * 16 + (lane & 15);
#pragma unroll
            for (int e = 0; e < 4; ++e) {
                const int row = (wid * 2 + i) * 16 + (lane >> 4) * 4 + e;
                z1p[((zb + row) * kR + r) * kO0 + col] = acc[i][j][e];
            }
        }
    }
}

// ---------------- PTP1 epilogue
__global__ __launch_bounds__(128)
void k_ptp1_post(const float* __restrict__ z1p, const float* __restrict__ factor,
                 const float* __restrict__ w, const float* __restrict__ bias,
                 float* __restrict__ f1) {
    const int b = blockIdx.x;
    const int n = blockIdx.y;
    const int o = threadIdx.x;
    __shared__ float part[2];
    float sv[kR], nrm[kR];
    const size_t zbase = ((size_t)n * kB + b) * kR * kO0;
    constexpr size_t kHalf = (size_t)8 * 256 * kR * kO0;
#pragma unroll
    for (int r = 0; r < kR; ++r) {
        float v = z1p[zbase + r * kO0 + o] + z1p[kHalf + zbase + r * kO0 + o]
                + 0.5f * factor[(size_t)(n * kR + r) * kD1 * kO0 + o];
        float a = fabsf(v);
        float s = copysignf(a * sqrtf(a), v);
        sv[r] = s;
        float t = s * s;
#pragma unroll
        for (int off = 1; off < 64; off <<= 1) t += __shfl_xor(t, off, 64);
        if ((threadIdx.x & 63) == 0) part[threadIdx.x >> 6] = t;
        __syncthreads();
        nrm[r] = sqrtf(part[0] + part[1]);
        __syncthreads();
    }
    float out = bias[n * kO0 + o];
#pragma unroll
    for (int r = 0; r < kR; ++r) out += w[n * kR + r] * sv[r] / nrm[r];
    f1[((size_t)b * kNW + n) * kO0 + o] = out;
}

// ---------------- PTP2 GEMM (k-split 2): z2p[ks][b][r][o]
__global__ __launch_bounds__(256)
void k_ptp2_gemm(const float* __restrict__ f1flat, const float* __restrict__ factor2,
                 float* __restrict__ z2p) {
    const int b0 = blockIdx.x * 32;
    const int r  = blockIdx.y;
    const int ks = blockIdx.z;
    const int tx = threadIdx.x & 63;
    const int ty = threadIdx.x >> 6;
    __shared__ float xs[32][128];
    float acc[8];
#pragma unroll
    for (int i = 0; i < 8; ++i) acc[i] = 0.f;
    const float* F = factor2 + (size_t)r * kD2 * kO1;
    const int kbeg = ks * 512;
    const int kend = ks ? kD2 : 512;

    for (int k0 = kbeg; k0 < kend; k0 += 128) {
        const int len = min(128, kend - k0);
        {
            const int row = threadIdx.x >> 3;
            const int c0  = (threadIdx.x & 7) * 16;
#pragma unroll
            for (int i = 0; i < 16; ++i) {
                int k = k0 + c0 + i;
                float v = (k == 0) ? 0.5f
                        : (k < kD2 ? f1flat[(size_t)(b0 + row) * 1024 + (k - 1)] : 0.f);
                xs[row][c0 + i] = v;
            }
        }
        __syncthreads();
        for (int dd = 0; dd < len; ++dd) {
            float wv = F[(size_t)(k0 + dd) * kO1 + tx];
#pragma unroll
            for (int i = 0; i < 8; ++i) acc[i] = fmaf(xs[ty * 8 + i][dd], wv, acc[i]);
        }
        __syncthreads();
    }
#pragma unroll
    for (int i = 0; i < 8; ++i) {
        const int b = b0 + ty * 8 + i;
        z2p[(size_t)ks * 262144 + ((size_t)b * kR + r) * kO1 + tx] = acc[i];
    }
}

// ---------------- PTP2 epilogue -> final output (B,64) fp32
__global__ __launch_bounds__(64)
void k_ptp2_post(const float* __restrict__ z2p, const float* __restrict__ w2,
                 const float* __restrict__ b2, float* __restrict__ out) {
    const int b = blockIdx.x;
    const int o = threadIdx.x;
    float sv[kR], nrm[kR];
#pragma unroll
    for (int r = 0; r < kR; ++r) {
        float v = z2p[((size_t)b * kR + r) * kO1 + o]
                + z2p[262144 + ((size_t)b * kR + r) * kO1 + o];
        float a = fabsf(v);
        float s = copysignf(a * sqrtf(a), v);
        sv[r] = s;
        float t = s * s;
#pragma unroll
        for (int off = 1; off < 64; off <<= 1) t += __shfl_xor(t, off, 64);
        nrm[r] = sqrtf(t);
    }
    float acc = b2[o];
#pragma unroll
    for (int r = 0; r < kR; ++r) acc += w2[r] * sv[r] / nrm[r];
    out[(size_t)b * kO1 + o] = acc;
}

// ---------------------------------------------------------------------------
extern "C" void kernel_launch(void* const* d_in, const int* in_sizes, int n_in,
                              void* d_out, int out_size, void* d_ws, size_t ws_size,
                              hipStream_t stream) {
    const float* audio_x  = (const float*)d_in[0];
    const float* video_x  = (const float*)d_in[1];
    const float* text_x   = (const float*)d_in[2];
    const float* aw_ih    = (const float*)d_in[3];
    const float* aw_hh    = (const float*)d_in[4];
    const float* ab_ih    = (const float*)d_in[5];
    const float* ab_hh    = (const float*)d_in[6];
    const float* vw_ih    = (const float*)d_in[7];
    const float* vw_hh    = (const float*)d_in[8];
    const float* vb_ih    = (const float*)d_in[9];
    const float* vb_hh    = (const float*)d_in[10];
    const float* txw_ih   = (const float*)d_in[11];
    const float* txw_hh   = (const float*)d_in[12];
    const float* txb_ih   = (const float*)d_in[13];
    const float* txb_hh   = (const float*)d_in[14];
    const float* l1_factor = (const float*)d_in[15];
    const float* l1_weight = (const float*)d_in[16];
    const float* l1_bias   = (const float*)d_in[17];
    const float* l2_factor = (const float*)d_in[18];
    const float* l2_weight = (const float*)d_in[19];
    const float* l2_bias   = (const float*)d_in[20];

    float* ws = (float*)d_ws;
    // workspace layout (float units; xp buffers hold bf16 in same-sized slots):
    unsigned short* xp_a = (unsigned short*)ws;               // (B*T,4H) bf16 permuted
    unsigned short* xp_v = (unsigned short*)(ws + 8388608);
    unsigned short* xp_t = (unsigned short*)(ws + 16777216);
    unsigned short* hp = (unsigned short*)(ws + 25165824);    // 6,291,456 bf16 (packed h)
    unsigned int* wfrag = (unsigned int*)(ws + 28311552);     //   393,216 u32 (frag W_hh)
    // post-LSTM aliases (xp buffers dead)
    float* z1p = ws;                           //  8,388,608  (2 k-split partials)
    float* f1  = ws + 8388608;                 //    262,144  (b,n,o)
    float* z2p = ws + 8388608 + 262144;        //    524,288  (2 partials)

    // 1) pack recurrent weights to MFMA fragment layout (gate-interleaved slabs)
    k_prep_wfrag<<<384, 256, 0, stream>>>(aw_hh, vw_hh, txw_hh, wfrag);

    // 2) input projections xp = x @ W_ih^T + b_ih + b_hh  (bf16 MFMA, bf16 out)
    dim3 gp(32, 8);
    k_mm_proj<<<gp, 512, 0, stream>>>(audio_x, aw_ih,  ab_ih,  ab_hh,  xp_a, 128);
    k_mm_proj<<<gp, 512, 0, stream>>>(video_x, vw_ih,  vb_ih,  vb_hh,  xp_v, 256);
    k_mm_proj<<<gp, 512, 0, stream>>>(text_x,  txw_ih, txb_ih, txb_hh, xp_t, 768);

    // 3) LSTM recurrence (register-ring W pipeline) -> hp (PTP1 fragment-packed)
    k_lstm7<<<dim3(16, 3), 1024, 0, stream>>>(xp_a, xp_v, xp_t, wfrag, hp);

    // 4) PTP layer 1
    k_ptp1_mfma<<<dim3(32, 8), 512, 0, stream>>>((const unsigned int*)hp, l1_factor, z1p);
    k_ptp1_post<<<dim3(256, 8), 128, 0, stream>>>(z1p, l1_factor, l1_weight, l1_bias, f1);

    // 5) PTP layer 2 -> output
    k_ptp2_gemm<<<dim3(8, 16, 2), 256, 0, stream>>>(f1, l2_factor, z2p);
    k_ptp2_post<<<256, 64, 0, stream>>>(z2p, l2_weight, l2_bias, (float*)d_out);
}

// Round 8
// 514.913 us; speedup vs baseline: 1.5707x; 1.5707x over previous
//
#include <hip/hip_runtime.h>
#include <hip/hip_bf16.h>

// ---------------------------------------------------------------------------
// Multimodal LSTM (x3) -> concat -> PTP layer1 (8 windows, rank 16) -> PTP layer2
// Round 8: revert to k_lstm6 (counted-DMA LDS ring, 206us proven) adapted to
// bf16 xp; ptp1 B-staging rewritten (coalesced dword loads -> single
// ds_write_b128, conflict-free pitch-80B layout); ptp1_post barrier-free.
// ---------------------------------------------------------------------------

namespace {
constexpr int kB  = 256;
constexpr int kT  = 32;
constexpr int kH  = 256;
constexpr int k4H = 1024;
constexpr int kNW = 8;
constexpr int kR  = 16;
constexpr int kO0 = 128;
constexpr int kO1 = 64;
constexpr int kD1 = 3073;   // 4*768 + 1
constexpr int kD2 = 1025;   // 8*128 + 1
}

typedef __attribute__((ext_vector_type(8))) short short8;   // 8 bf16 (4 VGPRs)
typedef __attribute__((ext_vector_type(4))) float f32x4;    // MFMA acc
typedef __attribute__((ext_vector_type(4))) unsigned int u32x4;

typedef const __attribute__((address_space(1))) unsigned int* gas_u32p;
typedef __attribute__((address_space(3))) unsigned int* las_u32p;

__device__ __forceinline__ unsigned int pack2bf(float a, float b) {
    unsigned int ua = __builtin_bit_cast(unsigned int, a);
    unsigned int ub = __builtin_bit_cast(unsigned int, b);
    return (ua >> 16) | (ub & 0xffff0000u);
}
__device__ __forceinline__ float bflo(unsigned int u) {
    return __builtin_bit_cast(float, u << 16);
}
__device__ __forceinline__ float bfhi(unsigned int u) {
    return __builtin_bit_cast(float, u & 0xffff0000u);
}
__device__ __forceinline__ float sigm(float x) {
    return 1.f / (1.f + __expf(-x));
}
__device__ __forceinline__ float tanh_fast(float x) {
    float a = fabsf(x);
    float t = 1.f - 2.f / (__expf(2.f * a) + 1.f);
    return copysignf(t, x);
}
__device__ __forceinline__ uint2 gload2u(const unsigned short* p) {
    uint2 r;
    asm volatile("global_load_dwordx2 %0, %1, off" : "=v"(r) : "v"(p) : "memory");
    return r;
}

// ---------------- W_hh (4H,H) fp32 -> MFMA-B-fragment-linear bf16.
// Slab (net,w,s): 4 KB = [gate g][lane l] u32x4; lane l holds
// col = g*256 + w*16 + (l&15), k = s*32 + (l>>4)*8 + [0..8).
__global__ void k_prep_wfrag(const float* __restrict__ wa, const float* __restrict__ wv,
                             const float* __restrict__ wtx, unsigned int* __restrict__ wfrag) {
    int g = blockIdx.x * 256 + threadIdx.x;     // 0 .. 98303
    int l  = g & 63;
    int gt = (g >> 6) & 3;
    int s  = (g >> 8) & 7;
    int w  = (g >> 11) & 15;
    int net = g >> 15;
    const float* W = (net == 0) ? wa : (net == 1) ? wv : wtx;
    const int col = gt * 256 + w * 16 + (l & 15);
    const int k0  = s * 32 + (l >> 4) * 8;
    const float* src = W + (size_t)col * 256 + k0;
    float4 f0 = *(const float4*)src;
    float4 f1 = *(const float4*)(src + 4);
    u32x4 v = { pack2bf(f0.x, f0.y), pack2bf(f0.z, f0.w),
                pack2bf(f1.x, f1.y), pack2bf(f1.z, f1.w) };
    *(u32x4*)&wfrag[(size_t)g * 4] = v;
}

// ---------------- MFMA GEMM (NT) for input projections, PERMUTED output cols,
// bf16 output: stored col n = w*64 + q*4 + g <-> orig gate-col g*256 + w*16 + q.
__global__ __launch_bounds__(512)
void k_mm_proj(const float* __restrict__ A, const float* __restrict__ W,
               const float* __restrict__ b1, const float* __restrict__ b2,
               unsigned short* __restrict__ C, int K) {
    __shared__ __align__(16) unsigned int As[256 * 20];
    __shared__ __align__(16) unsigned int Bs[128 * 20];
    const int tid  = threadIdx.x;
    const int lane = tid & 63;
    const int wid  = tid >> 6;
    const int wm   = wid >> 1, wn = wid & 1;
    const int m0 = blockIdx.x * 256, n0 = blockIdx.y * 128;
    const int nstep = K >> 5;

    const int ar = tid >> 1, akq = (tid & 1) * 16;
    const int br = tid >> 2, bkq = (tid & 3) * 8;
    const float* ap = A + (size_t)(m0 + ar) * K + akq;
    const int nn = n0 + br;
    const int worow = (nn & 3) * 256 + (nn >> 6) * 16 + ((nn >> 2) & 15);
    const float* wp = W + (size_t)worow * K + bkq;

    float4 aR[4], bR[2];
    auto loadA = [&](int s) {
#pragma unroll
        for (int i = 0; i < 4; ++i) aR[i] = *(const float4*)(ap + s * 32 + i * 4);
    };
    auto loadB = [&](int s) {
#pragma unroll
        for (int i = 0; i < 2; ++i) bR[i] = *(const float4*)(wp + s * 32 + i * 4);
    };

    f32x4 acc[4][4];
#pragma unroll
    for (int i = 0; i < 4; ++i)
#pragma unroll
        for (int j = 0; j < 4; ++j) acc[i][j] = (f32x4){0.f, 0.f, 0.f, 0.f};

    loadA(0); loadB(0);
    for (int s = 0; s < nstep; ++s) {
        __syncthreads();
        {
            u32x4 w0 = { pack2bf(aR[0].x, aR[0].y), pack2bf(aR[0].z, aR[0].w),
                         pack2bf(aR[1].x, aR[1].y), pack2bf(aR[1].z, aR[1].w) };
            u32x4 w1 = { pack2bf(aR[2].x, aR[2].y), pack2bf(aR[2].z, aR[2].w),
                         pack2bf(aR[3].x, aR[3].y), pack2bf(aR[3].z, aR[3].w) };
            *(u32x4*)&As[ar * 20 + (akq >> 1)]     = w0;
            *(u32x4*)&As[ar * 20 + (akq >> 1) + 4] = w1;
            u32x4 v0 = { pack2bf(bR[0].x, bR[0].y), pack2bf(bR[0].z, bR[0].w),
                         pack2bf(bR[1].x, bR[1].y), pack2bf(bR[1].z, bR[1].w) };
            *(u32x4*)&Bs[br * 20 + (bkq >> 1)] = v0;
        }
        __syncthreads();
        if (s + 1 < nstep) { loadA(s + 1); loadB(s + 1); }
        short8 af[4], bf[4];
#pragma unroll
        for (int i = 0; i < 4; ++i)
            af[i] = __builtin_bit_cast(short8,
                *(const u32x4*)&As[(wm * 64 + i * 16 + (lane & 15)) * 20 + (lane >> 4) * 4]);
#pragma unroll
        for (int j = 0; j < 4; ++j)
            bf[j] = __builtin_bit_cast(short8,
                *(const u32x4*)&Bs[(wn * 64 + j * 16 + (lane & 15)) * 20 + (lane >> 4) * 4]);
#pragma unroll
        for (int i = 0; i < 4; ++i)
#pragma unroll
            for (int j = 0; j < 4; ++j)
                acc[i][j] = __builtin_amdgcn_mfma_f32_16x16x32_bf16(af[i], bf[j], acc[i][j], 0, 0, 0);
    }
#pragma unroll
    for (int i = 0; i < 4; ++i) {
#pragma unroll
        for (int j = 0; j < 4; ++j) {
            const int col  = n0 + wn * 64 + j * 16 + (lane & 15);
            const int ocol = (col & 3) * 256 + (col >> 6) * 16 + ((col >> 2) & 15);
            const float badd = b1[ocol] + b2[ocol];
#pragma unroll
            for (int e = 0; e < 4; ++e) {
                const int row = m0 + wm * 64 + i * 16 + (lane >> 4) * 4 + e;
                const float v = acc[i][j][e] + badd;
                C[(size_t)row * 1024 + col] =
                    (unsigned short)(__builtin_bit_cast(unsigned int, v) >> 16);
            }
        }
    }
}

// ---------------- k_lstm6: MFMA recurrence, counted-DMA W pipeline (r6 proven),
// adapted to bf16 xp. Block = (net, 16 batch rows); 16 waves; wave w owns dims
// [16w,16w+16) of all 4 gates. W slabs DMA'd global->LDS into per-wave 2-slot
// rings; h in 2x8KB XOR-swizzled LDS; 1 raw barrier/step.
__global__ __launch_bounds__(1024, 4)
void k_lstm6(const unsigned short* __restrict__ xp_a, const unsigned short* __restrict__ xp_v,
             const unsigned short* __restrict__ xp_t, const unsigned int* __restrict__ wfrag,
             unsigned short* __restrict__ hp) {
    const int bg  = blockIdx.x;            // 0..15
    const int net = blockIdx.y;            // 0=audio,1=video,2=text
    const int tid = threadIdx.x;
    const int l   = tid & 63;
    const int w   = tid >> 6;              // wave -> dim-slice [16w,16w+16)
    const unsigned short* xp = (net == 0) ? xp_a : (net == 1) ? xp_v : xp_t;
    const int coloff = (net == 0) ? 256 : (net == 1) ? 512 : 0;  // cat=[text,audio,video]

    __shared__ __align__(16) unsigned short hA[8192];     // 2 x 8 KB, XOR-swizzled
    __shared__ __align__(16) unsigned int Wring[32768];   // 128 KB: wave w at [w*2048]

    for (int i = tid; i < 4096; i += 1024) ((unsigned int*)hA)[i] = 0u;

    const int q  = l & 15;
    const int r0 = (l >> 4) * 4;           // first of 4 batch rows this lane owns
    const int d  = w * 16 + q;             // dim within net

    const char* wbase = (const char*)wfrag + (size_t)(net * 16 + w) * 32768 + l * 16;
    unsigned int* wslot = &Wring[w * 2048];

    const unsigned short* xr0 = xp + ((size_t)(bg * 16 + r0) * 32) * 1024 + w * 64 + q * 4;

    const unsigned int rbase = (unsigned int)q * 512;
    const unsigned int rxor  = (unsigned int)(q & 7) << 4;
    const unsigned int kofs  = (unsigned int)(l >> 4) * 16;

    float cc[4] = {0.f, 0.f, 0.f, 0.f};

    auto issue_slab = [&](int slab, int slot) {
#pragma unroll
        for (int g = 0; g < 4; ++g) {
            const void* gp = (const void*)(wbase + slab * 4096 + g * 1024);
            void* lp = (void*)(wslot + slot * 1024 + g * 256);
            __builtin_amdgcn_global_load_lds(
                (gas_u32p)(size_t)gp,
                (las_u32p)(unsigned int)(size_t)lp, 16, 0, 0);
        }
    };

    // prologue: slabs 0,1 in flight; hA zeros visible
    issue_slab(0, 0);
    issue_slab(1, 1);
    asm volatile("s_waitcnt lgkmcnt(0)" ::: "memory");
    __builtin_amdgcn_s_barrier();

    for (int t = 0; t < kT; ++t) {
        // xp for this step (4 asm loads; retired by iter-2's vmcnt(4))
        const unsigned short* xr = xr0 + (size_t)t * 1024;
        uint2 xq0 = gload2u(xr);
        uint2 xq1 = gload2u(xr + 32768);
        uint2 xq2 = gload2u(xr + 65536);
        uint2 xq3 = gload2u(xr + 98304);

        const unsigned int rbuf = (unsigned int)(t & 1) * 8192;
        const unsigned int wbuf = 8192u - rbuf;

        f32x4 acc[4];
#pragma unroll
        for (int g = 0; g < 4; ++g) acc[g] = (f32x4){0.f, 0.f, 0.f, 0.f};

#pragma unroll
        for (int s = 0; s < 8; ++s) {
            // wait for slab s (its 4 DMA loads are the oldest in the window)
            if (s < 2) asm volatile("s_waitcnt vmcnt(8)" ::: "memory");
            else       asm volatile("s_waitcnt vmcnt(4)" ::: "memory");
            __builtin_amdgcn_sched_barrier(0);
            u32x4 af = *(const u32x4*)((const char*)hA + rbuf + rbase
                                       + (((unsigned)(s * 64) + kofs) ^ rxor));
            const unsigned int* wp = wslot + (s & 1) * 1024;
            u32x4 b0 = *(const u32x4*)(wp + 0 * 256 + l * 4);
            u32x4 b1 = *(const u32x4*)(wp + 1 * 256 + l * 4);
            u32x4 b2 = *(const u32x4*)(wp + 2 * 256 + l * 4);
            u32x4 b3 = *(const u32x4*)(wp + 3 * 256 + l * 4);
            acc[0] = __builtin_amdgcn_mfma_f32_16x16x32_bf16(
                __builtin_bit_cast(short8, af), __builtin_bit_cast(short8, b0), acc[0], 0, 0, 0);
            acc[1] = __builtin_amdgcn_mfma_f32_16x16x32_bf16(
                __builtin_bit_cast(short8, af), __builtin_bit_cast(short8, b1), acc[1], 0, 0, 0);
            acc[2] = __builtin_amdgcn_mfma_f32_16x16x32_bf16(
                __builtin_bit_cast(short8, af), __builtin_bit_cast(short8, b2), acc[2], 0, 0, 0);
            acc[3] = __builtin_amdgcn_mfma_f32_16x16x32_bf16(
                __builtin_bit_cast(short8, af), __builtin_bit_cast(short8, b3), acc[3], 0, 0, 0);
            __builtin_amdgcn_sched_barrier(0);
            // prefetch slab s+2 into the slot just consumed (wraps into next step)
            issue_slab((s + 2) & 7, s & 1);
        }

        // xq guaranteed retired; bounds outstanding DMA to the 2 prefetched slabs
        asm volatile("s_waitcnt vmcnt(8)" ::: "memory");
        __builtin_amdgcn_sched_barrier(0);

        // in-register activations: lane owns rows r0..r0+3 of dim d, all gates
        float hv[4];
        {
            float gi, gf, gg, go;
            gi = acc[0][0] + bflo(xq0.x); gf = acc[1][0] + bfhi(xq0.x);
            gg = acc[2][0] + bflo(xq0.y); go = acc[3][0] + bfhi(xq0.y);
            cc[0] = sigm(gf) * cc[0] + sigm(gi) * tanh_fast(gg); hv[0] = sigm(go) * tanh_fast(cc[0]);
            gi = acc[0][1] + bflo(xq1.x); gf = acc[1][1] + bfhi(xq1.x);
            gg = acc[2][1] + bflo(xq1.y); go = acc[3][1] + bfhi(xq1.y);
            cc[1] = sigm(gf) * cc[1] + sigm(gi) * tanh_fast(gg); hv[1] = sigm(go) * tanh_fast(cc[1]);
            gi = acc[0][2] + bflo(xq2.x); gf = acc[1][2] + bfhi(xq2.x);
            gg = acc[2][2] + bflo(xq2.y); go = acc[3][2] + bfhi(xq2.y);
            cc[2] = sigm(gf) * cc[2] + sigm(gi) * tanh_fast(gg); hv[2] = sigm(go) * tanh_fast(cc[2]);
            gi = acc[0][3] + bflo(xq3.x); gf = acc[1][3] + bfhi(xq3.x);
            gg = acc[2][3] + bflo(xq3.y); go = acc[3][3] + bfhi(xq3.y);
            cc[3] = sigm(gf) * cc[3] + sigm(gi) * tanh_fast(gg); hv[3] = sigm(go) * tanh_fast(cc[3]);
        }

        // stores: hA (next A operand, swizzled) + hp (PTP1 fragment layout)
        const int kk = (t & 3) * 768 + coloff + d;
        const int sp2 = kk >> 5;
        unsigned short* hpb = hp +
            ((((size_t)((t >> 2) * 96 + sp2) * 16 + bg) * 64
              + (unsigned)(r0 | (((kk >> 3) & 3) << 4))) * 8 + (kk & 7));
#pragma unroll
        for (int e = 0; e < 4; ++e) {
            const unsigned short hb =
                (unsigned short)(__builtin_bit_cast(unsigned int, hv[e]) >> 16);
            const int row = r0 + e;
            *(unsigned short*)((char*)hA + wbuf + (unsigned)row * 512
                               + (((unsigned)(2 * d)) ^ (((unsigned)(row & 7)) << 4))) = hb;
            hpb[e * 8] = hb;
        }
        asm volatile("s_waitcnt lgkmcnt(0)" ::: "memory");
        __builtin_amdgcn_s_barrier();
    }
}

// ---------------- PTP1 MFMA GEMM: z1p[ks][n][b][r][o] = sum_{d in ks-half} x*F
// A direct from hp (fragment-packed bf16); B: 8 coalesced dword loads ->
// in-thread pack -> single ds_write_b128, [o][chunk] pitch 80B (conflict-free).
__global__ __launch_bounds__(512)
void k_ptp1_mfma(const unsigned int* __restrict__ hp, const float* __restrict__ factor,
                 float* __restrict__ z1p) {
    __shared__ __align__(16) unsigned char Bs[128 * 80];   // [o:128][4 x 16B], pitch 80B
    const int tid  = threadIdx.x;
    const int lane = tid & 63;
    const int wid  = tid >> 6;
    const int r  = blockIdx.x >> 1;
    const int ks = blockIdx.x & 1;
    const int n  = blockIdx.y;

    const int bo = tid & 127;          // staged o
    const int bc = tid >> 7;           // d-chunk 0..3 (d = bc*8 + e)
    const float* fp = factor + ((size_t)(n * kR + r) * kD1 + 1 + ks * 1536 + bc * 8) * kO0 + bo;
    const unsigned int* ha = hp + ((size_t)n * 96 + ks * 48) * 16 * 256 + lane * 4;

    f32x4 acc[2][8];
#pragma unroll
    for (int i = 0; i < 2; ++i)
#pragma unroll
        for (int j = 0; j < 8; ++j) acc[i][j] = (f32x4){0.f, 0.f, 0.f, 0.f};

    float rB[2][8];
    u32x4 af[2][2];
    auto loadB = [&](int s, int qq) {
#pragma unroll
        for (int e = 0; e < 8; ++e)
            rB[qq][e] = fp[((size_t)s * 32 + e) * kO0];
    };
    auto loadA = [&](int s, int qq) {
#pragma unroll
        for (int i = 0; i < 2; ++i)
            af[qq][i] = *(const u32x4*)(ha + ((size_t)s * 16 + (wid * 2 + i)) * 256);
    };
    loadB(0, 0); loadA(0, 0);
#pragma unroll 2
    for (int s = 0; s < 48; ++s) {
        const int qq = s & 1;
        __syncthreads();
        {
            u32x4 pk = { pack2bf(rB[qq][0], rB[qq][1]), pack2bf(rB[qq][2], rB[qq][3]),
                         pack2bf(rB[qq][4], rB[qq][5]), pack2bf(rB[qq][6], rB[qq][7]) };
            *(u32x4*)(Bs + bo * 80 + bc * 16) = pk;
        }
        __syncthreads();
        if (s + 1 < 48) { loadB(s + 1, qq ^ 1); loadA(s + 1, qq ^ 1); }
        short8 bf[8];
#pragma unroll
        for (int j = 0; j < 8; ++j)
            bf[j] = __builtin_bit_cast(short8,
                *(const u32x4*)(Bs + (j * 16 + (lane & 15)) * 80 + (lane >> 4) * 16));
#pragma unroll
        for (int i = 0; i < 2; ++i)
#pragma unroll
            for (int j = 0; j < 8; ++j)
                acc[i][j] = __builtin_amdgcn_mfma_f32_16x16x32_bf16(
                    __builtin_bit_cast(short8, af[qq][i]), bf[j], acc[i][j], 0, 0, 0);
    }
    const size_t zb = ((size_t)ks * 8 + n) * 256;
#pragma unroll
    for (int i = 0; i < 2; ++i) {
#pragma unroll
        for (int j = 0; j < 8; ++j) {
            const int col = j * 16 + (lane & 15);
#pragma unroll
            for (int e = 0; e < 4; ++e) {
                const int row = (wid * 2 + i) * 16 + (lane >> 4) * 4 + e;
                z1p[((zb + row) * kR + r) * kO0 + col] = acc[i][j][e];
            }
        }
    }
}

// ---------------- PTP1 epilogue: barrier-free, 64 threads (o and o+64 per lane)
__global__ __launch_bounds__(64)
void k_ptp1_post(const float* __restrict__ z1p, const float* __restrict__ factor,
                 const float* __restrict__ w, const float* __restrict__ bias,
                 float* __restrict__ f1) {
    const int b = blockIdx.x;
    const int n = blockIdx.y;
    const int o = threadIdx.x;   // handles o and o+64
    float sv0[kR], sv1[kR], nrm[kR];
    const size_t zbase = ((size_t)n * kB + b) * kR * kO0;
    constexpr size_t kHalf = (size_t)8 * 256 * kR * kO0;
#pragma unroll
    for (int r = 0; r < kR; ++r) {
        const size_t zo = zbase + r * kO0 + o;
        const size_t fo = (size_t)(n * kR + r) * kD1 * kO0 + o;
        float v0 = z1p[zo] + z1p[kHalf + zo] + 0.5f * factor[fo];
        float v1 = z1p[zo + 64] + z1p[kHalf + zo + 64] + 0.5f * factor[fo + 64];
        float a0 = fabsf(v0), a1 = fabsf(v1);
        float s0 = copysignf(a0 * sqrtf(a0), v0);
        float s1 = copysignf(a1 * sqrtf(a1), v1);
        sv0[r] = s0; sv1[r] = s1;
        float t = s0 * s0 + s1 * s1;
#pragma unroll
        for (int off = 1; off < 64; off <<= 1) t += __shfl_xor(t, off, 64);
        nrm[r] = sqrtf(t);
    }
    float out0 = bias[n * kO0 + o];
    float out1 = bias[n * kO0 + o + 64];
#pragma unroll
    for (int r = 0; r < kR; ++r) {
        const float wr = w[n * kR + r];
        out0 += wr * sv0[r] / nrm[r];
        out1 += wr * sv1[r] / nrm[r];
    }
    f1[((size_t)b * kNW + n) * kO0 + o] = out0;
    f1[((size_t)b * kNW + n) * kO0 + o + 64] = out1;
}

// ---------------- PTP2 GEMM (k-split 2): z2p[ks][b][r][o]
__global__ __launch_bounds__(256)
void k_ptp2_gemm(const float* __restrict__ f1flat, const float* __restrict__ factor2,
                 float* __restrict__ z2p) {
    const int b0 = blockIdx.x * 32;
    const int r  = blockIdx.y;
    const int ks = blockIdx.z;
    const int tx = threadIdx.x & 63;
    const int ty = threadIdx.x >> 6;
    __shared__ float xs[32][128];
    float acc[8];
#pragma unroll
    for (int i = 0; i < 8; ++i) acc[i] = 0.f;
    const float* F = factor2 + (size_t)r * kD2 * kO1;
    const int kbeg = ks * 512;
    const int kend = ks ? kD2 : 512;

    for (int k0 = kbeg; k0 < kend; k0 += 128) {
        const int len = min(128, kend - k0);
        {
            const int row = threadIdx.x >> 3;
            const int c0  = (threadIdx.x & 7) * 16;
#pragma unroll
            for (int i = 0; i < 16; ++i) {
                int k = k0 + c0 + i;
                float v = (k == 0) ? 0.5f
                        : (k < kD2 ? f1flat[(size_t)(b0 + row) * 1024 + (k - 1)] : 0.f);
                xs[row][c0 + i] = v;
            }
        }
        __syncthreads();
        for (int dd = 0; dd < len; ++dd) {
            float wv = F[(size_t)(k0 + dd) * kO1 + tx];
#pragma unroll
            for (int i = 0; i < 8; ++i) acc[i] = fmaf(xs[ty * 8 + i][dd], wv, acc[i]);
        }
        __syncthreads();
    }
#pragma unroll
    for (int i = 0; i < 8; ++i) {
        const int b = b0 + ty * 8 + i;
        z2p[(size_t)ks * 262144 + ((size_t)b * kR + r) * kO1 + tx] = acc[i];
    }
}

// ---------------- PTP2 epilogue -> final output (B,64) fp32
__global__ __launch_bounds__(64)
void k_ptp2_post(const float* __restrict__ z2p, const float* __restrict__ w2,
                 const float* __restrict__ b2, float* __restrict__ out) {
    const int b = blockIdx.x;
    const int o = threadIdx.x;
    float sv[kR], nrm[kR];
#pragma unroll
    for (int r = 0; r < kR; ++r) {
        float v = z2p[((size_t)b * kR + r) * kO1 + o]
                + z2p[262144 + ((size_t)b * kR + r) * kO1 + o];
        float a = fabsf(v);
        float s = copysignf(a * sqrtf(a), v);
        sv[r] = s;
        float t = s * s;
#pragma unroll
        for (int off = 1; off < 64; off <<= 1) t += __shfl_xor(t, off, 64);
        nrm[r] = sqrtf(t);
    }
    float acc = b2[o];
#pragma unroll
    for (int r = 0; r < kR; ++r) acc += w2[r] * sv[r] / nrm[r];
    out[(size_t)b * kO1 + o] = acc;
}

// ---------------------------------------------------------------------------
extern "C" void kernel_launch(void* const* d_in, const int* in_sizes, int n_in,
                              void* d_out, int out_size, void* d_ws, size_t ws_size,
                              hipStream_t stream) {
    const float* audio_x  = (const float*)d_in[0];
    const float* video_x  = (const float*)d_in[1];
    const float* text_x   = (const float*)d_in[2];
    const float* aw_ih    = (const float*)d_in[3];
    const float* aw_hh    = (const float*)d_in[4];
    const float* ab_ih    = (const float*)d_in[5];
    const float* ab_hh    = (const float*)d_in[6];
    const float* vw_ih    = (const float*)d_in[7];
    const float* vw_hh    = (const float*)d_in[8];
    const float* vb_ih    = (const float*)d_in[9];
    const float* vb_hh    = (const float*)d_in[10];
    const float* txw_ih   = (const float*)d_in[11];
    const float* txw_hh   = (const float*)d_in[12];
    const float* txb_ih   = (const float*)d_in[13];
    const float* txb_hh   = (const float*)d_in[14];
    const float* l1_factor = (const float*)d_in[15];
    const float* l1_weight = (const float*)d_in[16];
    const float* l1_bias   = (const float*)d_in[17];
    const float* l2_factor = (const float*)d_in[18];
    const float* l2_weight = (const float*)d_in[19];
    const float* l2_bias   = (const float*)d_in[20];

    float* ws = (float*)d_ws;
    // workspace layout (float units; xp buffers hold bf16 in same-sized slots):
    unsigned short* xp_a = (unsigned short*)ws;               // (B*T,4H) bf16 permuted
    unsigned short* xp_v = (unsigned short*)(ws + 8388608);
    unsigned short* xp_t = (unsigned short*)(ws + 16777216);
    unsigned short* hp = (unsigned short*)(ws + 25165824);    // 6,291,456 bf16 (packed h)
    unsigned int* wfrag = (unsigned int*)(ws + 28311552);     //   393,216 u32 (frag W_hh)
    // post-LSTM aliases (xp buffers dead)
    float* z1p = ws;                           //  8,388,608  (2 k-split partials)
    float* f1  = ws + 8388608;                 //    262,144  (b,n,o)
    float* z2p = ws + 8388608 + 262144;        //    524,288  (2 partials)

    // 1) pack recurrent weights to MFMA fragment layout (gate-interleaved slabs)
    k_prep_wfrag<<<384, 256, 0, stream>>>(aw_hh, vw_hh, txw_hh, wfrag);

    // 2) input projections xp = x @ W_ih^T + b_ih + b_hh  (bf16 MFMA, bf16 out)
    dim3 gp(32, 8);
    k_mm_proj<<<gp, 512, 0, stream>>>(audio_x, aw_ih,  ab_ih,  ab_hh,  xp_a, 128);
    k_mm_proj<<<gp, 512, 0, stream>>>(video_x, vw_ih,  vb_ih,  vb_hh,  xp_v, 256);
    k_mm_proj<<<gp, 512, 0, stream>>>(text_x,  txw_ih, txb_ih, txb_hh, xp_t, 768);

    // 3) LSTM recurrence (counted-DMA W pipeline) -> hp (PTP1 fragment-packed)
    k_lstm6<<<dim3(16, 3), 1024, 0, stream>>>(xp_a, xp_v, xp_t, wfrag, hp);

    // 4) PTP layer 1
    k_ptp1_mfma<<<dim3(32, 8), 512, 0, stream>>>((const unsigned int*)hp, l1_factor, z1p);
    k_ptp1_post<<<dim3(256, 8), 64, 0, stream>>>(z1p, l1_factor, l1_weight, l1_bias, f1);

    // 5) PTP layer 2 -> output
    k_ptp2_gemm<<<dim3(8, 16, 2), 256, 0, stream>>>(f1, l2_factor, z2p);
    k_ptp2_post<<<256, 64, 0, stream>>>(z2p, l2_weight, l2_bias, (float*)d_out);
}